// Round 4
// baseline (119.632 us; speedup 1.0000x reference)
//
#include <hip/hip_runtime.h>

typedef float f32x4 __attribute__((ext_vector_type(4)));
typedef int   i32x4 __attribute__((ext_vector_type(4)));

// x: [1, 2049, 8192] f32 ; lambda: [1, 8192] f32
// out: [1, 1+2048+8192, 8192] f32
//   row 0           : center = lam*x0 - 0.5*lam*lower
//   rows 1..2048    : x[e]*lam
//   rows 2049..10240: extra[r][n] = (rows[n]==r) ? -0.5*lam*lower : 0

// K1: fused errs-scale + per-row-chunk abs partial sums.
// grid (N/1024, PBY), block 256, each thread owns 4 contiguous columns.
__global__ __launch_bounds__(256) void k_errs_partial(
    const float* __restrict__ x, const float* __restrict__ lam,
    float* __restrict__ out, float* __restrict__ partials,
    int N, int rowsPerBlock)
{
    const int col = (blockIdx.x * 256 + threadIdx.x) * 4;
    const int r0  = 1 + blockIdx.y * rowsPerBlock;
    const f32x4 l4 = *(const f32x4*)(lam + col);
    f32x4 acc = {0.f, 0.f, 0.f, 0.f};
    #pragma unroll 4
    for (int r = r0; r < r0 + rowsPerBlock; ++r) {
        const f32x4 v = *(const f32x4*)(x + (size_t)r * N + col);
        acc.x += fabsf(v.x); acc.y += fabsf(v.y); acc.z += fabsf(v.z); acc.w += fabsf(v.w);
        *(f32x4*)(out + (size_t)r * N + col) = v * l4;
    }
    *(f32x4*)(partials + (size_t)blockIdx.y * N + col) = acc;
}

// K2: reduce partials per column, write center (out row 0), flags, vals.
__global__ __launch_bounds__(256) void k_stats(
    const float* __restrict__ x, const float* __restrict__ lam,
    const float* __restrict__ partials,
    float* __restrict__ out, float* __restrict__ vals, int* __restrict__ flags,
    int N, int P)
{
    const int n = blockIdx.x * 256 + threadIdx.x;
    float s = 0.f;
    for (int p = 0; p < P; ++p) s += partials[(size_t)p * N + n];
    const float x0 = x[n];          // row 0 of x
    const float l  = lam[n];
    const float lower = x0 - s;
    const float upper = x0 + s;
    out[n] = l * x0 - l * lower * 0.5f;          // center
    const bool has = (lower < 0.f) && (upper > 0.f);
    flags[n] = has ? 1 : 0;
    vals[n]  = has ? (-l * lower * 0.5f) : 0.f;
}

// K3: single-block (256 threads) prefix scan of flags -> compacted row idx (or -1).
__global__ __launch_bounds__(256) void k_scan(
    const int* __restrict__ flags, int* __restrict__ rowsArr, int N)
{
    __shared__ int waveSums[4];
    const int t    = threadIdx.x;
    const int per  = N / 256;         // 32
    const int base = t * per;
    int f[32];
    int cnt = 0;
    #pragma unroll
    for (int i = 0; i < 32; ++i) { f[i] = flags[base + i]; cnt += f[i]; }
    // inclusive shfl scan across the 64-lane wave
    const int lane = t & 63;
    const int wid  = t >> 6;
    int v = cnt;
    #pragma unroll
    for (int off = 1; off < 64; off <<= 1) {
        const int u = __shfl_up(v, off, 64);
        if (lane >= off) v += u;
    }
    if (lane == 63) waveSums[wid] = v;
    __syncthreads();
    int wadd = 0;
    for (int w = 0; w < wid; ++w) wadd += waveSums[w];
    int run = v - cnt + wadd;         // exclusive prefix for this thread
    #pragma unroll
    for (int i = 0; i < 32; ++i) {
        rowsArr[base + i] = f[i] ? run : -1;
        run += f[i];
    }
}

// K4: write the N x N extra block: (rows[n]==r) ? vals[n] : 0.
// grid (N/1024, N/rowsPerBlock), block 256, 4 cols/thread; rows/vals stay in regs.
__global__ __launch_bounds__(256) void k_extra(
    const float* __restrict__ vals, const int* __restrict__ rowsArr,
    float* __restrict__ outExtra, int N, int rowsPerBlock)
{
    const int col = (blockIdx.x * 256 + threadIdx.x) * 4;
    const int r0  = blockIdx.y * rowsPerBlock;
    const i32x4 rw = *(const i32x4*)(rowsArr + col);
    const f32x4 vv = *(const f32x4*)(vals + col);
    for (int r = r0; r < r0 + rowsPerBlock; ++r) {
        f32x4 o;
        o.x = (rw.x == r) ? vv.x : 0.f;
        o.y = (rw.y == r) ? vv.y : 0.f;
        o.z = (rw.z == r) ? vv.z : 0.f;
        o.w = (rw.w == r) ? vv.w : 0.f;
        *(f32x4*)(outExtra + (size_t)r * N + col) = o;
    }
}

extern "C" void kernel_launch(void* const* d_in, const int* in_sizes, int n_in,
                              void* d_out, int out_size, void* d_ws, size_t ws_size,
                              hipStream_t stream) {
    const float* x   = (const float*)d_in[0];
    const float* lam = (const float*)d_in[1];
    float* out = (float*)d_out;

    const int N  = in_sizes[1];            // 8192
    const int E1 = in_sizes[0] / N;        // 2049
    const int E  = E1 - 1;                 // 2048

    // Pick the largest partial-chunk count that fits the workspace.
    // PBY must divide E. Prefer 128 (4 blocks/CU in K1).
    const size_t smallBytes = (size_t)3 * N * 4;   // vals + flags + rowsArr
    int PBY = 32;
    for (int cand : {128, 64, 32}) {
        if ((E % cand) == 0 && ((size_t)cand * N * 4 + smallBytes) <= ws_size) { PBY = cand; break; }
    }

    float* partials = (float*)d_ws;                     // [PBY][N]
    float* vals     = partials + (size_t)PBY * N;       // [N]
    int*   flags    = (int*)(vals + N);                 // [N]
    int*   rowsArr  = flags + N;                        // [N]

    dim3 blk(256);

    dim3 g1(N / 1024, PBY);
    hipLaunchKernelGGL(k_errs_partial, g1, blk, 0, stream,
                       x, lam, out, partials, N, E / PBY);

    hipLaunchKernelGGL(k_stats, dim3(N / 256), blk, 0, stream,
                       x, lam, partials, out, vals, flags, N, PBY);

    hipLaunchKernelGGL(k_scan, dim3(1), blk, 0, stream,
                       flags, rowsArr, N);

    dim3 g3(N / 1024, N / 32);
    hipLaunchKernelGGL(k_extra, g3, blk, 0, stream,
                       vals, rowsArr, out + (size_t)E1 * N, N, 32);
}

// Round 5
// 96.122 us; speedup vs baseline: 1.2446x; 1.2446x over previous
//
#include <hip/hip_runtime.h>

typedef float f32x4 __attribute__((ext_vector_type(4)));

// x: [1, 2049, 8192] f32 ; lambda: [1, 8192] f32
// out: [1, 1+2048+8192, 8192] f32
//   row 0           : center = lam*x0 - 0.5*lam*lower
//   rows 1..2048    : x[e]*lam
//   rows 2049..10240: extra[r][n] = (colOfRow[r]==n) ? -0.5*lam*lower : 0

// K1: fused errs-scale + per-row-chunk abs partial sums.
// grid (N/1024, PBY), block 256, each thread owns 4 contiguous columns,
// streams rowsPerBlock rows (long per-thread runs; PBY=32 proven best).
__global__ __launch_bounds__(256) void k_errs_partial(
    const float* __restrict__ x, const float* __restrict__ lam,
    float* __restrict__ out, float* __restrict__ partials,
    int N, int rowsPerBlock)
{
    const int col = (blockIdx.x * 256 + threadIdx.x) * 4;
    const int r0  = 1 + blockIdx.y * rowsPerBlock;
    const f32x4 l4 = *(const f32x4*)(lam + col);
    f32x4 acc = {0.f, 0.f, 0.f, 0.f};
    #pragma unroll 4
    for (int r = r0; r < r0 + rowsPerBlock; ++r) {
        const f32x4 v = __builtin_nontemporal_load((const f32x4*)(x + (size_t)r * N + col));
        acc.x += fabsf(v.x); acc.y += fabsf(v.y); acc.z += fabsf(v.z); acc.w += fabsf(v.w);
        __builtin_nontemporal_store(v * l4, (f32x4*)(out + (size_t)r * N + col));
    }
    *(f32x4*)(partials + (size_t)blockIdx.y * N + col) = acc;
}

// K2: reduce partials per column, write center (out row 0), flags, vals.
__global__ __launch_bounds__(256) void k_stats(
    const float* __restrict__ x, const float* __restrict__ lam,
    const float* __restrict__ partials,
    float* __restrict__ out, float* __restrict__ vals, int* __restrict__ flags,
    int N, int P)
{
    const int n = blockIdx.x * 256 + threadIdx.x;
    float s = 0.f;
    for (int p = 0; p < P; ++p) s += partials[(size_t)p * N + n];
    const float x0 = x[n];          // row 0 of x
    const float l  = lam[n];
    const float lower = x0 - s;
    const float upper = x0 + s;
    out[n] = l * x0 - l * lower * 0.5f;          // center
    const bool has = (lower < 0.f) && (upper > 0.f);
    flags[n] = has ? 1 : 0;
    vals[n]  = has ? (-l * lower * 0.5f) : 0.f;
}

// K3: single-block (256 threads) scan of flags -> inverse map colOfRow:
// colOfRow[r] = n such that (cumsum(flags)-1)[n] == r, else -1.
__global__ __launch_bounds__(256) void k_scan(
    const int* __restrict__ flags, int* __restrict__ colOfRow, int N)
{
    __shared__ int waveSums[4];
    const int t    = threadIdx.x;
    const int per  = N / 256;         // 32
    const int base = t * per;
    int f[32];
    int cnt = 0;
    #pragma unroll
    for (int i = 0; i < 32; ++i) {
        f[i] = flags[base + i];
        cnt += f[i];
        colOfRow[base + i] = -1;      // init; ordered vs scatter by the barrier below
    }
    // inclusive shfl scan across the 64-lane wave
    const int lane = t & 63;
    const int wid  = t >> 6;
    int v = cnt;
    #pragma unroll
    for (int off = 1; off < 64; off <<= 1) {
        const int u = __shfl_up(v, off, 64);
        if (lane >= off) v += u;
    }
    if (lane == 63) waveSums[wid] = v;
    __syncthreads();                  // orders colOfRow=-1 init + waveSums
    int wadd = 0;
    for (int w = 0; w < wid; ++w) wadd += waveSums[w];
    int run = v - cnt + wadd;         // exclusive prefix for this thread
    #pragma unroll
    for (int i = 0; i < 32; ++i) {
        if (f[i]) { colOfRow[run] = base + i; run += 1; }
    }
}

// K4: extra block, row-owned: block b fills rows [b*rpb, (b+1)*rpb) — a fully
// CONTIGUOUS 256 KB region — with zeros (NT stores), injecting vals[c] at the
// single column c = colOfRow[r] per row. Same linear pattern as the 7 TB/s fill.
__global__ __launch_bounds__(256) void k_extra_rows(
    const float* __restrict__ vals, const int* __restrict__ colOfRow,
    float* __restrict__ outExtra, int N, int rowsPerBlock)
{
    const int t  = threadIdx.x;
    const int r0 = blockIdx.x * rowsPerBlock;
    const int sweeps = N / 1024;      // 8 (256 threads x 4 floats)
    for (int r = r0; r < r0 + rowsPerBlock; ++r) {
        const int   c  = colOfRow[r];             // broadcast scalar read
        const float vv = (c >= 0) ? vals[c] : 0.f;
        float* rowp = outExtra + (size_t)r * N;
        #pragma unroll
        for (int s = 0; s < 8; ++s) {
            const int col = (s * 256 + t) * 4;
            f32x4 o;
            o.x = (c == col    ) ? vv : 0.f;
            o.y = (c == col + 1) ? vv : 0.f;
            o.z = (c == col + 2) ? vv : 0.f;
            o.w = (c == col + 3) ? vv : 0.f;
            __builtin_nontemporal_store(o, (f32x4*)(rowp + col));
        }
        (void)sweeps;
    }
}

extern "C" void kernel_launch(void* const* d_in, const int* in_sizes, int n_in,
                              void* d_out, int out_size, void* d_ws, size_t ws_size,
                              hipStream_t stream) {
    const float* x   = (const float*)d_in[0];
    const float* lam = (const float*)d_in[1];
    float* out = (float*)d_out;

    const int N  = in_sizes[1];            // 8192
    const int E1 = in_sizes[0] / N;        // 2049
    const int E  = E1 - 1;                 // 2048

    const int PBY = 32;                    // proven best (R1 A/B vs R4)

    float* partials = (float*)d_ws;                     // [PBY][N]
    float* vals     = partials + (size_t)PBY * N;       // [N]
    int*   flags    = (int*)(vals + N);                 // [N]
    int*   colOfRow = flags + N;                        // [N]

    dim3 blk(256);

    dim3 g1(N / 1024, PBY);
    hipLaunchKernelGGL(k_errs_partial, g1, blk, 0, stream,
                       x, lam, out, partials, N, E / PBY);

    hipLaunchKernelGGL(k_stats, dim3(N / 256), blk, 0, stream,
                       x, lam, partials, out, vals, flags, N, PBY);

    hipLaunchKernelGGL(k_scan, dim3(1), blk, 0, stream,
                       flags, colOfRow, N);

    const int rpb = 8;                     // 1024 blocks, 256 KB linear per block
    hipLaunchKernelGGL(k_extra_rows, dim3(N / rpb), blk, 0, stream,
                       vals, colOfRow, out + (size_t)E1 * N, N, rpb);
}